// Round 5
// baseline (419.916 us; speedup 1.0000x reference)
//
#include <hip/hip_runtime.h>
#include <hip/hip_bf16.h>
#include <hip/hip_cooperative_groups.h>
#include <math.h>

namespace cg = cooperative_groups;

// Problem constants (fixed by the reference):
//   D=5 directions, E=16 experts, B=64 batch, P=4096 patches/expert, W=3 window
//   Q,K,V: [D,E,B,P] f32; betas: [E,E] f32; temperature: [1] f32; routes: [E,W] int
//   out: [B, E*P] f32, out[b, e*P+p] = mean_d softmax_w(Q*c)_w . Vnbr_w
//
// Preferred path: ONE cooperative kernel (overlaps the K/V reduction stream
// with the Q stream; 264 MB combined -> ~38 us floor). If the cooperative
// launch is rejected (return code != hipSuccess), fall back to the proven
// two-kernel path (R0, 50.7 us). The branch is environment-determined, so
// it is the same on every call -> deterministic.

#define D_ 5
#define E_ 16
#define B_ 64
#define P_ 4096
#define W_ 3
#define ROWS (D_*E_*B_)   // 5120 rows = 1024 blocks * 5

typedef float f32x4 __attribute__((ext_vector_type(4)));

__device__ __forceinline__ float attend1(float q, const float c[3], const float v[3])
{
    float s0 = q * c[0], s1 = q * c[1], s2 = q * c[2];
    float m  = fmaxf(fmaxf(s0, s1), s2);
    float e0 = __expf(s0 - m), e1 = __expf(s1 - m), e2 = __expf(s2 - m);
    float num = e0 * v[0] + e1 * v[1] + e2 * v[2];
    float den = e0 + e1 + e2;
    return __fdividef(num, den);
}

// ---------------- fused cooperative kernel ----------------
__global__ __launch_bounds__(256, 4) void cga_fused(
    const float* __restrict__ Q,
    const float* __restrict__ K, const float* __restrict__ V,
    const float* __restrict__ betas, const float* __restrict__ temp,
    const int* __restrict__ routes,
    float* __restrict__ ksum, float* __restrict__ vmean,
    float* __restrict__ out)
{
    const int t    = threadIdx.x;
    const int wid  = t >> 6;
    const int lane = t & 63;

    __shared__ float skk[5][4], svv[5][4];   // per-row, per-wave partials
    __shared__ float sc[D_][W_], sv[D_][W_]; // phase-B coefficients

    // ---------------- Phase A: 5 rows of K,V per block ----------------
    #pragma unroll
    for (int i = 0; i < 5; ++i) {
        const int row = blockIdx.x * 5 + i;
        const f32x4* k4 = (const f32x4*)(K + (size_t)row * P_);
        const f32x4* v4 = (const f32x4*)(V + (size_t)row * P_);
        f32x4 a[4], c[4];
        #pragma unroll
        for (int j = 0; j < 4; ++j) a[j] = k4[t + j * 256];
        #pragma unroll
        for (int j = 0; j < 4; ++j) c[j] = v4[t + j * 256];
        float ks = 0.f, vs = 0.f;
        #pragma unroll
        for (int j = 0; j < 4; ++j) {
            ks += (a[j][0] + a[j][1]) + (a[j][2] + a[j][3]);
            vs += (c[j][0] + c[j][1]) + (c[j][2] + c[j][3]);
        }
        #pragma unroll
        for (int off = 32; off > 0; off >>= 1) {
            ks += __shfl_down(ks, off);
            vs += __shfl_down(vs, off);
        }
        if (lane == 0) { skk[i][wid] = ks; svv[i][wid] = vs; }
    }
    __syncthreads();
    if (t < 5) {
        const int row = blockIdx.x * 5 + t;
        float kk = (skk[t][0] + skk[t][1]) + (skk[t][2] + skk[t][3]);
        float vv = (svv[t][0] + svv[t][1]) + (svv[t][2] + svv[t][3]);
        ksum[row]  = kk;
        vmean[row] = vv * (1.0f / (float)P_);
    }
    __threadfence();                 // release: push ksum/vmean out of this XCD's L2

    cg::this_grid().sync();

    __threadfence();                 // acquire: invalidate possibly-stale lines

    // ---------------- Phase B: one (e,b) pair per block ----------------
    const int b = blockIdx.x & (B_ - 1);
    const int e = blockIdx.x >> 6;

    if (t < D_ * W_) {
        const int d = t / W_;
        const int w = t - d * W_;
        const int rw = routes[e * W_ + w];
        const float scale = 1.0f / (11.313708498984760f * fabsf(temp[0])); // sqrt(128)
        float bw = 1.0f;
        if (rw != e) bw = 1.0f / (1.0f + __expf(-betas[e * E_ + rw]));
        const int idx = (d * E_ + rw) * B_ + b;
        sc[d][w] = ksum[idx] * scale * bw;
        sv[d][w] = vmean[idx];
    }
    __syncthreads();

    f32x4 acc[4] = {{0,0,0,0},{0,0,0,0},{0,0,0,0},{0,0,0,0}};
    #pragma unroll
    for (int d = 0; d < D_; ++d) {
        const float* qp = Q + ((size_t)((d * E_ + e) * B_ + b)) * P_ + t * 4;
        f32x4 q[4];
        #pragma unroll
        for (int c = 0; c < 4; ++c) q[c] = *(const f32x4*)(qp + c * 1024);
        float rc[W_], rv[W_];
        #pragma unroll
        for (int w = 0; w < W_; ++w) { rc[w] = sc[d][w]; rv[w] = sv[d][w]; }
        #pragma unroll
        for (int c = 0; c < 4; ++c)
            #pragma unroll
            for (int j = 0; j < 4; ++j)
                acc[c][j] += attend1(q[c][j], rc, rv);
    }
    const float inv_d = 1.0f / (float)D_;
    float* ob = out + (size_t)b * (E_ * P_) + (size_t)e * P_ + t * 4;
    #pragma unroll
    for (int c = 0; c < 4; ++c) {
        acc[c][0] *= inv_d; acc[c][1] *= inv_d; acc[c][2] *= inv_d; acc[c][3] *= inv_d;
        *(f32x4*)(ob + c * 1024) = acc[c];
    }
}

// ---------------- fallback: proven two-kernel path (R0) ----------------
__global__ __launch_bounds__(256) void cga_phase1(
    const float* __restrict__ K, const float* __restrict__ V,
    float* __restrict__ ksum, float* __restrict__ vmean)
{
    const int row = blockIdx.x;
    const f32x4* k4 = (const f32x4*)(K + (size_t)row * P_);
    const f32x4* v4 = (const f32x4*)(V + (size_t)row * P_);
    const int t = threadIdx.x;

    f32x4 a[4], c[4];
    #pragma unroll
    for (int i = 0; i < 4; ++i) a[i] = k4[t + i * 256];
    #pragma unroll
    for (int i = 0; i < 4; ++i) c[i] = v4[t + i * 256];
    float ks = 0.f, vs = 0.f;
    #pragma unroll
    for (int i = 0; i < 4; ++i) {
        ks += (a[i][0] + a[i][1]) + (a[i][2] + a[i][3]);
        vs += (c[i][0] + c[i][1]) + (c[i][2] + c[i][3]);
    }
    #pragma unroll
    for (int off = 32; off > 0; off >>= 1) {
        ks += __shfl_down(ks, off);
        vs += __shfl_down(vs, off);
    }
    __shared__ float sk[4], sv[4];
    const int wid = t >> 6, lane = t & 63;
    if (lane == 0) { sk[wid] = ks; sv[wid] = vs; }
    __syncthreads();
    if (t == 0) {
        ksum[row]  = (sk[0] + sk[1]) + (sk[2] + sk[3]);
        vmean[row] = ((sv[0] + sv[1]) + (sv[2] + sv[3])) * (1.0f / (float)P_);
    }
}

__global__ __launch_bounds__(256) void cga_phase2(
    const float* __restrict__ Q,
    const float* __restrict__ ksum, const float* __restrict__ vmean,
    const float* __restrict__ betas, const float* __restrict__ temp,
    const int* __restrict__ routes,
    float* __restrict__ out)
{
    const int blk   = blockIdx.x;
    const int chunk = blk & 3;
    const int eb    = blk >> 2;
    const int b     = eb & (B_ - 1);
    const int e     = eb >> 6;
    const int t     = threadIdx.x;

    __shared__ float sc[D_][W_], sv[D_][W_];
    if (t < D_ * W_) {
        const int d = t / W_;
        const int w = t - d * W_;
        const int rw = routes[e * W_ + w];
        const float scale = 1.0f / (11.313708498984760f * fabsf(temp[0]));
        float bw = 1.0f;
        if (rw != e) bw = 1.0f / (1.0f + __expf(-betas[e * E_ + rw]));
        const int idx = (d * E_ + rw) * B_ + b;
        sc[d][w] = ksum[idx] * scale * bw;
        sv[d][w] = vmean[idx];
    }
    __syncthreads();

    const int p0 = chunk * 1024 + t * 4;
    f32x4 acc = {0,0,0,0};
    #pragma unroll
    for (int d = 0; d < D_; ++d) {
        const f32x4 q = *(const f32x4*)(Q + ((size_t)((d * E_ + e) * B_ + b)) * P_ + p0);
        float rc[W_], rv[W_];
        #pragma unroll
        for (int w = 0; w < W_; ++w) { rc[w] = sc[d][w]; rv[w] = sv[d][w]; }
        #pragma unroll
        for (int j = 0; j < 4; ++j) acc[j] += attend1(q[j], rc, rv);
    }
    const float inv_d = 1.0f / (float)D_;
    #pragma unroll
    for (int j = 0; j < 4; ++j) acc[j] *= inv_d;
    *(f32x4*)(out + (size_t)b * (E_ * P_) + (size_t)e * P_ + p0) = acc;
}

extern "C" void kernel_launch(void* const* d_in, const int* in_sizes, int n_in,
                              void* d_out, int out_size, void* d_ws, size_t ws_size,
                              hipStream_t stream) {
    const float* Q     = (const float*)d_in[0];
    const float* K     = (const float*)d_in[1];
    const float* V     = (const float*)d_in[2];
    const float* betas = (const float*)d_in[3];
    const float* temp  = (const float*)d_in[4];
    const int*   routes= (const int*)d_in[5];
    float* out = (float*)d_out;

    float* ksum  = (float*)d_ws;          // ROWS floats
    float* vmean = ksum + ROWS;           // ROWS floats  (40 KB total)

    void* args[] = { (void*)&Q, (void*)&K, (void*)&V, (void*)&betas,
                     (void*)&temp, (void*)&routes,
                     (void*)&ksum, (void*)&vmean, (void*)&out };
    hipError_t err = hipLaunchCooperativeKernel((const void*)cga_fused,
                                                dim3(ROWS / 5), dim3(256),
                                                args, 0, stream);
    if (err != hipSuccess) {
        // environment rejects cooperative launch -> proven two-kernel path
        cga_phase1<<<ROWS, 256, 0, stream>>>(K, V, ksum, vmean);
        cga_phase2<<<E_ * B_ * (P_ / 1024), 256, 0, stream>>>(
            Q, ksum, vmean, betas, temp, routes, out);
    }
}

// Round 6
// 52.765 us; speedup vs baseline: 7.9582x; 7.9582x over previous
//
#include <hip/hip_runtime.h>
#include <hip/hip_bf16.h>
#include <math.h>

// Problem constants (fixed by the reference):
//   D=5 directions, E=16 experts, B=64 batch, P=4096 patches/expert, W=3 window
//   Q,K,V: [D,E,B,P] f32; betas: [E,E] f32; temperature: [1] f32; routes: [E,W] int
//   out: [B, E*P] f32, out[b, e*P+p] = mean_d softmax_w(Q*c)_w . Vnbr_w
//
// Structure (proven R0 two-kernel path, 50.7 us):
//   phase1: Ksum/Vmean row reductions  (168 MB single-use -> non-temporal)
//   phase2: Q-streaming 3-way softmax  (Q re-read every call -> cacheable)
// R5 change: phase1 processes TWO rows per block (16 float4 in flight/thread,
// grid 2560) for deeper MLP; everything else is R0 verbatim.

#define D_ 5
#define E_ 16
#define B_ 64
#define P_ 4096
#define W_ 3
#define ROWS (D_*E_*B_)   // 5120 (d,e,b) rows

typedef float f32x4 __attribute__((ext_vector_type(4)));

// ---------------- Phase 1: Ksum / Vmean row reductions ----------------
// two rows per block; 256 threads; 16 non-temporal float4 loads per thread
__global__ __launch_bounds__(256) void cga_phase1(
    const float* __restrict__ K, const float* __restrict__ V,
    float* __restrict__ ksum, float* __restrict__ vmean)
{
    const int r0 = blockIdx.x * 2;              // rows r0, r0+1
    const int t  = threadIdx.x;
    const f32x4* k0 = (const f32x4*)(K + (size_t)r0 * P_);
    const f32x4* v0 = (const f32x4*)(V + (size_t)r0 * P_);
    const f32x4* k1 = (const f32x4*)(K + (size_t)(r0 + 1) * P_);
    const f32x4* v1 = (const f32x4*)(V + (size_t)(r0 + 1) * P_);

    f32x4 a0[4], a1[4], c0[4], c1[4];
    #pragma unroll
    for (int i = 0; i < 4; ++i) a0[i] = __builtin_nontemporal_load(&k0[t + i * 256]);
    #pragma unroll
    for (int i = 0; i < 4; ++i) a1[i] = __builtin_nontemporal_load(&k1[t + i * 256]);
    #pragma unroll
    for (int i = 0; i < 4; ++i) c0[i] = __builtin_nontemporal_load(&v0[t + i * 256]);
    #pragma unroll
    for (int i = 0; i < 4; ++i) c1[i] = __builtin_nontemporal_load(&v1[t + i * 256]);

    float ks0 = 0.f, vs0 = 0.f, ks1 = 0.f, vs1 = 0.f;
    #pragma unroll
    for (int i = 0; i < 4; ++i) {
        ks0 += (a0[i][0] + a0[i][1]) + (a0[i][2] + a0[i][3]);
        ks1 += (a1[i][0] + a1[i][1]) + (a1[i][2] + a1[i][3]);
        vs0 += (c0[i][0] + c0[i][1]) + (c0[i][2] + c0[i][3]);
        vs1 += (c1[i][0] + c1[i][1]) + (c1[i][2] + c1[i][3]);
    }
    // wave-64 tree reduce (4 values)
    #pragma unroll
    for (int off = 32; off > 0; off >>= 1) {
        ks0 += __shfl_down(ks0, off);
        ks1 += __shfl_down(ks1, off);
        vs0 += __shfl_down(vs0, off);
        vs1 += __shfl_down(vs1, off);
    }
    __shared__ float sk0[4], sk1[4], sv0[4], sv1[4];
    const int wid = t >> 6, lane = t & 63;
    if (lane == 0) { sk0[wid] = ks0; sk1[wid] = ks1; sv0[wid] = vs0; sv1[wid] = vs1; }
    __syncthreads();
    if (t == 0) {
        ksum[r0]      = (sk0[0] + sk0[1]) + (sk0[2] + sk0[3]);
        vmean[r0]     = ((sv0[0] + sv0[1]) + (sv0[2] + sv0[3])) * (1.0f / (float)P_);
        ksum[r0 + 1]  = (sk1[0] + sk1[1]) + (sk1[2] + sk1[3]);
        vmean[r0 + 1] = ((sv1[0] + sv1[1]) + (sv1[2] + sv1[3])) * (1.0f / (float)P_);
    }
}

// ---------------- Phase 2: stream Q, 3-way softmax, mean over d ----------------
// (R0 verbatim: 4096 blocks, 4 floats/thread, coeffs via LDS)
__device__ __forceinline__ float attend1(float q, const float c[3], const float v[3])
{
    float s0 = q * c[0], s1 = q * c[1], s2 = q * c[2];
    float m  = fmaxf(fmaxf(s0, s1), s2);
    float e0 = __expf(s0 - m), e1 = __expf(s1 - m), e2 = __expf(s2 - m);
    float num = e0 * v[0] + e1 * v[1] + e2 * v[2];
    float den = e0 + e1 + e2;
    return num / den;
}

__global__ __launch_bounds__(256) void cga_phase2(
    const float* __restrict__ Q,
    const float* __restrict__ ksum, const float* __restrict__ vmean,
    const float* __restrict__ betas, const float* __restrict__ temp,
    const int* __restrict__ routes,
    float* __restrict__ out)
{
    const int blk   = blockIdx.x;
    const int chunk = blk & 3;        // 4 chunks of 1024 patches per (e,b)
    const int eb    = blk >> 2;
    const int b     = eb & (B_ - 1);
    const int e     = eb >> 6;
    const int t     = threadIdx.x;

    __shared__ float sc[D_][W_];      // score coeffs  c[d][w] = Ksum*scale*beta
    __shared__ float sv[D_][W_];      // value coeffs  v[d][w] = Vmean
    if (t < D_ * W_) {
        const int d = t / W_;
        const int w = t - d * W_;
        const int rw = routes[e * W_ + w];
        const float scale = 1.0f / (11.313708498984760f * fabsf(temp[0])); // sqrt(128)
        float bw = 1.0f;
        if (rw != e) bw = 1.0f / (1.0f + __expf(-betas[e * E_ + rw]));
        const int idx = (d * E_ + rw) * B_ + b;
        sc[d][w] = ksum[idx] * scale * bw;
        sv[d][w] = vmean[idx];
    }
    __syncthreads();

    float rc[D_][W_], rv[D_][W_];
    #pragma unroll
    for (int d = 0; d < D_; ++d)
        #pragma unroll
        for (int w = 0; w < W_; ++w) { rc[d][w] = sc[d][w]; rv[d][w] = sv[d][w]; }

    const int p0 = chunk * 1024 + t * 4;

    f32x4 acc = {0.f, 0.f, 0.f, 0.f};
    #pragma unroll
    for (int d = 0; d < D_; ++d) {
        const size_t qoff = ((size_t)((d * E_ + e) * B_ + b)) * P_ + p0;
        const f32x4 q = *(const f32x4*)(Q + qoff);
        #pragma unroll
        for (int j = 0; j < 4; ++j) acc[j] += attend1(q[j], rc[d], rv[d]);
    }
    const float inv_d = 1.0f / (float)D_;
    #pragma unroll
    for (int j = 0; j < 4; ++j) acc[j] *= inv_d;

    *(f32x4*)(out + (size_t)b * (E_ * P_) + (size_t)e * P_ + p0) = acc;
}

extern "C" void kernel_launch(void* const* d_in, const int* in_sizes, int n_in,
                              void* d_out, int out_size, void* d_ws, size_t ws_size,
                              hipStream_t stream) {
    const float* Q     = (const float*)d_in[0];
    const float* K     = (const float*)d_in[1];
    const float* V     = (const float*)d_in[2];
    const float* betas = (const float*)d_in[3];
    const float* temp  = (const float*)d_in[4];
    const int*   routes= (const int*)d_in[5];
    float* out = (float*)d_out;

    float* ksum  = (float*)d_ws;          // ROWS floats
    float* vmean = ksum + ROWS;           // ROWS floats  (40 KB total)

    cga_phase1<<<ROWS / 2, 256, 0, stream>>>(K, V, ksum, vmean);
    cga_phase2<<<E_ * B_ * (P_ / 1024), 256, 0, stream>>>(
        Q, ksum, vmean, betas, temp, routes, out);
}

// Round 7
// 51.699 us; speedup vs baseline: 8.1223x; 1.0206x over previous
//
#include <hip/hip_runtime.h>
#include <hip/hip_bf16.h>
#include <math.h>

// Problem constants (fixed by the reference):
//   D=5 directions, E=16 experts, B=64 batch, P=4096 patches/expert, W=3 window
//   Q,K,V: [D,E,B,P] f32; betas: [E,E] f32; temperature: [1] f32; routes: [E,W] int
//   out: [B, E*P] f32, out[b, e*P+p] = mean_d softmax_w(Q*c)_w . Vnbr_w
//
// R6: phase1 at HALF-ROW granularity (10240 blocks -> 40 blocks/CU, full
// 32-wave occupancy) writing partial sums; phase2 (R0-verbatim config) adds
// the two partials in its 15-element coefficient gather.

#define D_ 5
#define E_ 16
#define B_ 64
#define P_ 4096
#define W_ 3
#define ROWS (D_*E_*B_)   // 5120 (d,e,b) rows

typedef float f32x4 __attribute__((ext_vector_type(4)));

// ---------------- Phase 1 (split): half-row per block ----------------
// block blk: row = blk>>1, half = blk&1. 256 threads x 4 float4 loads.
// Writes kpart[half*ROWS+row], vpart[half*ROWS+row] (raw sums).
__global__ __launch_bounds__(256) void cga_phase1_split(
    const float* __restrict__ K, const float* __restrict__ V,
    float* __restrict__ kpart, float* __restrict__ vpart)
{
    const int blk = blockIdx.x;               // [0, 10240)
    const int row = blk >> 1;
    const int h   = blk & 1;
    const int t   = threadIdx.x;
    const f32x4* k4 = (const f32x4*)(K + (size_t)row * P_ + h * (P_ / 2));
    const f32x4* v4 = (const f32x4*)(V + (size_t)row * P_ + h * (P_ / 2));

    f32x4 a[2], c[2];
    a[0] = k4[t]; a[1] = k4[t + 256];
    c[0] = v4[t]; c[1] = v4[t + 256];

    float ks = (a[0][0] + a[0][1]) + (a[0][2] + a[0][3])
             + (a[1][0] + a[1][1]) + (a[1][2] + a[1][3]);
    float vs = (c[0][0] + c[0][1]) + (c[0][2] + c[0][3])
             + (c[1][0] + c[1][1]) + (c[1][2] + c[1][3]);

    #pragma unroll
    for (int off = 32; off > 0; off >>= 1) {
        ks += __shfl_down(ks, off);
        vs += __shfl_down(vs, off);
    }
    __shared__ float sk[4], sv[4];
    const int wid = t >> 6, lane = t & 63;
    if (lane == 0) { sk[wid] = ks; sv[wid] = vs; }
    __syncthreads();
    if (t == 0) {
        kpart[h * ROWS + row] = (sk[0] + sk[1]) + (sk[2] + sk[3]);
        vpart[h * ROWS + row] = (sv[0] + sv[1]) + (sv[2] + sv[3]);
    }
}

// ---------------- Phase 1 (fallback, R0-verbatim): full row per block ----------------
__global__ __launch_bounds__(256) void cga_phase1_full(
    const float* __restrict__ K, const float* __restrict__ V,
    float* __restrict__ kpart, float* __restrict__ vpart)
{
    const int row = blockIdx.x;
    const f32x4* k4 = (const f32x4*)(K + (size_t)row * P_);
    const f32x4* v4 = (const f32x4*)(V + (size_t)row * P_);
    const int t = threadIdx.x;

    f32x4 a[4], c[4];
    #pragma unroll
    for (int i = 0; i < 4; ++i) a[i] = k4[t + i * 256];
    #pragma unroll
    for (int i = 0; i < 4; ++i) c[i] = v4[t + i * 256];
    float ks = 0.f, vs = 0.f;
    #pragma unroll
    for (int i = 0; i < 4; ++i) {
        ks += (a[i][0] + a[i][1]) + (a[i][2] + a[i][3]);
        vs += (c[i][0] + c[i][1]) + (c[i][2] + c[i][3]);
    }
    #pragma unroll
    for (int off = 32; off > 0; off >>= 1) {
        ks += __shfl_down(ks, off);
        vs += __shfl_down(vs, off);
    }
    __shared__ float sk[4], sv[4];
    const int wid = t >> 6, lane = t & 63;
    if (lane == 0) { sk[wid] = ks; sv[wid] = vs; }
    __syncthreads();
    if (t == 0) {
        kpart[row] = (sk[0] + sk[1]) + (sk[2] + sk[3]);
        vpart[row] = (sv[0] + sv[1]) + (sv[2] + sv[3]);
    }
}

// ---------------- Phase 2: stream Q, 3-way softmax, mean over d ----------------
// R0-verbatim except the gather sums `split+1` partial planes.
__device__ __forceinline__ float attend1(float q, const float c[3], const float v[3])
{
    float s0 = q * c[0], s1 = q * c[1], s2 = q * c[2];
    float m  = fmaxf(fmaxf(s0, s1), s2);
    float e0 = __expf(s0 - m), e1 = __expf(s1 - m), e2 = __expf(s2 - m);
    float num = e0 * v[0] + e1 * v[1] + e2 * v[2];
    float den = e0 + e1 + e2;
    return num / den;
}

__global__ __launch_bounds__(256) void cga_phase2(
    const float* __restrict__ Q,
    const float* __restrict__ kpart, const float* __restrict__ vpart,
    const float* __restrict__ betas, const float* __restrict__ temp,
    const int* __restrict__ routes, const int split,
    float* __restrict__ out)
{
    const int blk   = blockIdx.x;
    const int chunk = blk & 3;        // 4 chunks of 1024 patches per (e,b)
    const int eb    = blk >> 2;
    const int b     = eb & (B_ - 1);
    const int e     = eb >> 6;
    const int t     = threadIdx.x;

    __shared__ float sc[D_][W_];      // score coeffs  c[d][w] = Ksum*scale*beta
    __shared__ float sv[D_][W_];      // value coeffs  v[d][w] = Vmean
    if (t < D_ * W_) {
        const int d = t / W_;
        const int w = t - d * W_;
        const int rw = routes[e * W_ + w];
        const float scale = 1.0f / (11.313708498984760f * fabsf(temp[0])); // sqrt(128)
        float bw = 1.0f;
        if (rw != e) bw = 1.0f / (1.0f + __expf(-betas[e * E_ + rw]));
        const int idx = (d * E_ + rw) * B_ + b;
        float kk = kpart[idx], vv = vpart[idx];
        if (split) { kk += kpart[ROWS + idx]; vv += vpart[ROWS + idx]; }
        sc[d][w] = kk * scale * bw;
        sv[d][w] = vv * (1.0f / (float)P_);
    }
    __syncthreads();

    float rc[D_][W_], rv[D_][W_];
    #pragma unroll
    for (int d = 0; d < D_; ++d)
        #pragma unroll
        for (int w = 0; w < W_; ++w) { rc[d][w] = sc[d][w]; rv[d][w] = sv[d][w]; }

    const int p0 = chunk * 1024 + t * 4;

    f32x4 acc = {0.f, 0.f, 0.f, 0.f};
    #pragma unroll
    for (int d = 0; d < D_; ++d) {
        const size_t qoff = ((size_t)((d * E_ + e) * B_ + b)) * P_ + p0;
        const f32x4 q = *(const f32x4*)(Q + qoff);
        #pragma unroll
        for (int j = 0; j < 4; ++j) acc[j] += attend1(q[j], rc[d], rv[d]);
    }
    const float inv_d = 1.0f / (float)D_;
    #pragma unroll
    for (int j = 0; j < 4; ++j) acc[j] *= inv_d;

    *(f32x4*)(out + (size_t)b * (E_ * P_) + (size_t)e * P_ + p0) = acc;
}

extern "C" void kernel_launch(void* const* d_in, const int* in_sizes, int n_in,
                              void* d_out, int out_size, void* d_ws, size_t ws_size,
                              hipStream_t stream) {
    const float* Q     = (const float*)d_in[0];
    const float* K     = (const float*)d_in[1];
    const float* V     = (const float*)d_in[2];
    const float* betas = (const float*)d_in[3];
    const float* temp  = (const float*)d_in[4];
    const int*   routes= (const int*)d_in[5];
    float* out = (float*)d_out;

    const int split = (ws_size >= (size_t)(4 * ROWS) * sizeof(float)) ? 1 : 0;
    float* kpart = (float*)d_ws;                       // [split+1][ROWS]
    float* vpart = kpart + (split ? 2 * ROWS : ROWS);  // [split+1][ROWS]

    if (split) {
        cga_phase1_split<<<ROWS * 2, 256, 0, stream>>>(K, V, kpart, vpart);
    } else {
        cga_phase1_full<<<ROWS, 256, 0, stream>>>(K, V, kpart, vpart);
    }
    cga_phase2<<<E_ * B_ * (P_ / 1024), 256, 0, stream>>>(
        Q, kpart, vpart, betas, temp, routes, split, out);
}